// Round 3
// baseline (81.862 us; speedup 1.0000x reference)
//
#include <hip/hip_runtime.h>
#include <hip/hip_bf16.h>

// Problem constants (fixed by the reference)
#define B_DIM   8
#define S_LEN   4096
#define H_DIM   1024
#define HID_DIM 128
#define NSPEC   5
#define NROWS   (HID_DIM + 1 + NSPEC)   // 129 interval rows + 5 special rows = 134
#define SLOPE   0.01f
#define LN_EPS  1e-12f

// ---------------------------------------------------------------------------
// Kernel 1: build table rows.
//   rows 0..128 : interval i -> (u_i, v_i) with expr_e(x) = x*u + v (b2 folded)
//   rows 129..133: special m -> (0, leaky(special_emb[m]) @ W2 + b2)
// grid (NROWS), 256 threads; thread handles 4 consecutive output columns.
// Block 0 additionally publishes the raw breakpoints t_k (unsorted) for fuse.
// Interval membership in fuse is the count #{k: t_k <= x}, which is
// order-independent -> no sorting needed anywhere outside rank-internal use.
// ---------------------------------------------------------------------------
__global__ __launch_bounds__(256) void build_kernel(
        const float* __restrict__ W1,
        const float* __restrict__ b1,
        const float* __restrict__ W2,
        const float* __restrict__ b2,
        const float* __restrict__ spec,
        float* __restrict__ tvals,
        float2* __restrict__ tab) {
    const int row = blockIdx.x;
    const int tid = threadIdx.x;

    __shared__ float tsh[HID_DIM];
    __shared__ float ash[HID_DIM];
    __shared__ float csh[HID_DIM];

    float w = 0.0f, b = 0.0f, t = 0.0f;
    if (tid < HID_DIM) {
        w = W1[tid];
        b = b1[tid];
        t = (w != 0.0f) ? (-b / w) : __builtin_inff();
        tsh[tid] = t;
        if (row == 0) tvals[tid] = t;    // raw breakpoints for the fuse ballot
    }
    __syncthreads();
    if (tid < HID_DIM) {
        // stable rank of t among all breakpoints (defines interval membership)
        int r = 0;
        #pragma unroll 8
        for (int k2 = 0; k2 < HID_DIM; ++k2) {
            const float t2 = tsh[k2];
            if (t2 < t || (t2 == t && k2 < tid)) ++r;
        }

        float a, c;
        if (row <= HID_DIM) {
            const bool crossed = (r < row);              // t_k <= x in interval
            bool zpos;
            if (w > 0.0f)      zpos = crossed;
            else if (w < 0.0f) zpos = !crossed;
            else               zpos = (b >= 0.0f);
            const float s = zpos ? 1.0f : (SLOPE * SLOPE);
            a = s * w;
            c = s * b;
        } else {
            const int m = row - (HID_DIM + 1);
            const float e = spec[m * HID_DIM + tid];
            a = 0.0f;
            c = (e >= 0.0f) ? e : SLOPE * e;
        }
        ash[tid] = a;
        csh[tid] = c;
    }
    __syncthreads();

    // thread handles columns [4*tid .. 4*tid+3]
    float4 u = make_float4(0.f, 0.f, 0.f, 0.f);
    float4 v = make_float4(0.f, 0.f, 0.f, 0.f);
    #pragma unroll 4
    for (int k = 0; k < HID_DIM; ++k) {
        const float4 w2 = reinterpret_cast<const float4*>(W2 + (size_t)k * H_DIM)[tid];
        const float a = ash[k], c = csh[k];
        u.x = fmaf(a, w2.x, u.x);  v.x = fmaf(c, w2.x, v.x);
        u.y = fmaf(a, w2.y, u.y);  v.y = fmaf(c, w2.y, v.y);
        u.z = fmaf(a, w2.z, u.z);  v.z = fmaf(c, w2.z, v.z);
        u.w = fmaf(a, w2.w, u.w);  v.w = fmaf(c, w2.w, v.w);
    }
    const float4 bb = reinterpret_cast<const float4*>(b2)[tid];
    float4* trow = reinterpret_cast<float4*>(tab + (size_t)row * H_DIM);
    trow[2 * tid]     = make_float4(u.x, v.x + bb.x, u.y, v.y + bb.y);
    trow[2 * tid + 1] = make_float4(u.z, v.z + bb.z, u.w, v.w + bb.w);
}

// ---------------------------------------------------------------------------
// Kernel 2: fused gather + table-lookup MLP + pos add + LayerNorm.
// Wave-per-token, 4 waves (4 tokens) per 256-thread block.
// Zero LDS, zero barriers. Interval index via ballot+popcount (x is
// wave-uniform so the ballot is a 64-lane count of t_k <= x).
// ---------------------------------------------------------------------------
__global__ __launch_bounds__(256) void fuse_kernel(
        const int*   __restrict__ gene_ids,
        const float* __restrict__ expr,
        const float* __restrict__ gene_emb,
        const float* __restrict__ pos_emb,
        const float* __restrict__ gamma,
        const float* __restrict__ beta,
        const float* __restrict__ tvals,
        const float2* __restrict__ tab,
        float* __restrict__ out) {
    const int tid  = threadIdx.x;
    const int lane = tid & 63;
    const int t    = blockIdx.x * 4 + (tid >> 6);   // token index
    const int s    = t & (S_LEN - 1);               // S = 4096 (pow2)

    // independent loads first: token scalars, breakpoints, then the big rows
    const float x   = expr[t];                      // wave-uniform broadcast
    const int   gid = gene_ids[t];
    const float tk0 = tvals[lane];                  // breakpoint k = lane
    const float tk1 = tvals[lane + 64];             // breakpoint k = lane+64

    const float4* gp = reinterpret_cast<const float4*>(gene_emb + (size_t)gid * H_DIM);
    const float4* pp = reinterpret_cast<const float4*>(pos_emb  + (size_t)s   * H_DIM);
    const float4* gmp = reinterpret_cast<const float4*>(gamma);
    const float4* btp = reinterpret_cast<const float4*>(beta);

    float4 g[4], p[4], gm[4], bt[4];
    #pragma unroll
    for (int q = 0; q < 4; ++q) {
        const int f = lane + 64 * q;
        g[q]  = gp[f];
        p[q]  = pp[f];
        gm[q] = gmp[f];
        bt[q] = btp[f];
    }

    // interval index: row = #{k : t_k <= x}; O(1) via two ballots
    const unsigned long long m0 = __ballot(tk0 <= x);
    const unsigned long long m1 = __ballot(tk1 <= x);
    const int row_cont = __popcll(m0) + __popcll(m1);

    const bool special = (x < 0.0f);
    int msp = -((int)x) - 1;                        // trunc-toward-zero == astype
    msp = min(max(msp, 0), NSPEC - 1);
    const int   row = special ? (HID_DIM + 1 + msp) : row_cont;
    const float xm  = special ? 0.0f : x;           // special u-rows are zero

    const float4* tp = reinterpret_cast<const float4*>(tab + (size_t)row * H_DIM);
    float4 e[4];
    float s1 = 0.0f, s2 = 0.0f;
    #pragma unroll
    for (int q = 0; q < 4; ++q) {
        const int f = lane + 64 * q;
        const float4 ta = tp[2 * f];       // (u0, v0, u1, v1)
        const float4 tb = tp[2 * f + 1];   // (u2, v2, u3, v3)
        float4 ev;
        ev.x = g[q].x + fmaf(xm, ta.x, ta.y) + p[q].x;
        ev.y = g[q].y + fmaf(xm, ta.z, ta.w) + p[q].y;
        ev.z = g[q].z + fmaf(xm, tb.x, tb.y) + p[q].z;
        ev.w = g[q].w + fmaf(xm, tb.z, tb.w) + p[q].w;
        e[q] = ev;
        s1 += ev.x + ev.y + ev.z + ev.w;
        s2 += ev.x * ev.x + ev.y * ev.y + ev.z * ev.z + ev.w * ev.w;
    }

    // 64-lane butterfly reduction (no LDS, no barrier)
    #pragma unroll
    for (int off = 32; off >= 1; off >>= 1) {
        s1 += __shfl_xor(s1, off, 64);
        s2 += __shfl_xor(s2, off, 64);
    }

    const float inv  = 1.0f / (float)H_DIM;
    const float mu   = s1 * inv;
    const float var  = s2 * inv - mu * mu;
    const float rsig = rsqrtf(var + LN_EPS);

    float4* op = reinterpret_cast<float4*>(out + (size_t)t * H_DIM);
    #pragma unroll
    for (int q = 0; q < 4; ++q) {
        const int f = lane + 64 * q;
        float4 o;
        o.x = fmaf((e[q].x - mu) * rsig, gm[q].x, bt[q].x);
        o.y = fmaf((e[q].y - mu) * rsig, gm[q].y, bt[q].y);
        o.z = fmaf((e[q].z - mu) * rsig, gm[q].z, bt[q].z);
        o.w = fmaf((e[q].w - mu) * rsig, gm[q].w, bt[q].w);
        op[f] = o;
    }
}

// ---------------------------------------------------------------------------
extern "C" void kernel_launch(void* const* d_in, const int* in_sizes, int n_in,
                              void* d_out, int out_size, void* d_ws, size_t ws_size,
                              hipStream_t stream) {
    const int*   gene_ids = (const int*)  d_in[0];
    const float* expr     = (const float*)d_in[1];
    const float* gene_emb = (const float*)d_in[2];
    const float* W1       = (const float*)d_in[3];
    const float* b1       = (const float*)d_in[4];
    const float* W2       = (const float*)d_in[5];
    const float* b2       = (const float*)d_in[6];
    const float* spec     = (const float*)d_in[7];
    const float* pos_emb  = (const float*)d_in[8];
    const float* gamma    = (const float*)d_in[9];
    const float* beta     = (const float*)d_in[10];
    float* out = (float*)d_out;

    // workspace layout
    const size_t tab_bytes = (size_t)NROWS * H_DIM * sizeof(float2);  // ~1.07 MB
    float2* tab   = (float2*)d_ws;
    float*  tvals = (float*)((char*)d_ws + tab_bytes);

    const int n_tokens = in_sizes[0];   // B*S = 32768

    build_kernel<<<NROWS, 256, 0, stream>>>(W1, b1, W2, b2, spec, tvals, tab);
    fuse_kernel<<<n_tokens / 4, 256, 0, stream>>>(gene_ids, expr, gene_emb, pos_emb,
                                                  gamma, beta, tvals, tab, out);
}

// Round 5
// 73.999 us; speedup vs baseline: 1.1063x; 1.1063x over previous
//
#include <hip/hip_runtime.h>
#include <hip/hip_bf16.h>

// Problem constants (fixed by the reference)
#define B_DIM   8
#define S_LEN   4096
#define H_DIM   1024
#define HID_DIM 128
#define NSPEC   5
#define NROWS   (HID_DIM + 1 + NSPEC)   // 129 interval rows + 5 special rows = 134
#define SLOPE   0.01f
#define LN_EPS  1e-12f

// native clang vector for nontemporal stores (HIP float4 is a class type,
// which __builtin_nontemporal_store rejects)
typedef float vfloat4 __attribute__((ext_vector_type(4)));

// ---------------------------------------------------------------------------
// Kernel 1: build table rows.
//   rows 0..128 : interval i -> (u_i, v_i) with expr_e(x) = x*u + v (b2 folded)
//   rows 129..133: special m -> (0, leaky(special_emb[m]) @ W2 + b2)
// Block 0 additionally publishes the raw breakpoints t_k (unsorted) for fuse;
// interval membership there is the order-independent count #{k: t_k <= x}.
// ---------------------------------------------------------------------------
__global__ __launch_bounds__(256) void build_kernel(
        const float* __restrict__ W1,
        const float* __restrict__ b1,
        const float* __restrict__ W2,
        const float* __restrict__ b2,
        const float* __restrict__ spec,
        float* __restrict__ tvals,
        float2* __restrict__ tab) {
    const int row = blockIdx.x;
    const int tid = threadIdx.x;

    __shared__ float tsh[HID_DIM];
    __shared__ float ash[HID_DIM];
    __shared__ float csh[HID_DIM];

    float w = 0.0f, b = 0.0f, t = 0.0f;
    if (tid < HID_DIM) {
        w = W1[tid];
        b = b1[tid];
        t = (w != 0.0f) ? (-b / w) : __builtin_inff();
        tsh[tid] = t;
        if (row == 0) tvals[tid] = t;    // raw breakpoints for the fuse ballot
    }
    __syncthreads();
    if (tid < HID_DIM) {
        // stable rank of t among all breakpoints (defines interval membership)
        int r = 0;
        #pragma unroll 8
        for (int k2 = 0; k2 < HID_DIM; ++k2) {
            const float t2 = tsh[k2];
            if (t2 < t || (t2 == t && k2 < tid)) ++r;
        }

        float a, c;
        if (row <= HID_DIM) {
            const bool crossed = (r < row);              // t_k <= x in interval
            bool zpos;
            if (w > 0.0f)      zpos = crossed;
            else if (w < 0.0f) zpos = !crossed;
            else               zpos = (b >= 0.0f);
            const float s = zpos ? 1.0f : (SLOPE * SLOPE);
            a = s * w;
            c = s * b;
        } else {
            const int m = row - (HID_DIM + 1);
            const float e = spec[m * HID_DIM + tid];
            a = 0.0f;
            c = (e >= 0.0f) ? e : SLOPE * e;
        }
        ash[tid] = a;
        csh[tid] = c;
    }
    __syncthreads();

    // thread handles columns [4*tid .. 4*tid+3]
    float4 u = make_float4(0.f, 0.f, 0.f, 0.f);
    float4 v = make_float4(0.f, 0.f, 0.f, 0.f);
    #pragma unroll 4
    for (int k = 0; k < HID_DIM; ++k) {
        const float4 w2 = reinterpret_cast<const float4*>(W2 + (size_t)k * H_DIM)[tid];
        const float a = ash[k], c = csh[k];
        u.x = fmaf(a, w2.x, u.x);  v.x = fmaf(c, w2.x, v.x);
        u.y = fmaf(a, w2.y, u.y);  v.y = fmaf(c, w2.y, v.y);
        u.z = fmaf(a, w2.z, u.z);  v.z = fmaf(c, w2.z, v.z);
        u.w = fmaf(a, w2.w, u.w);  v.w = fmaf(c, w2.w, v.w);
    }
    const float4 bb = reinterpret_cast<const float4*>(b2)[tid];
    float4* trow = reinterpret_cast<float4*>(tab + (size_t)row * H_DIM);
    trow[2 * tid]     = make_float4(u.x, v.x + bb.x, u.y, v.y + bb.y);
    trow[2 * tid + 1] = make_float4(u.z, v.z + bb.z, u.w, v.w + bb.w);
}

// ---------------------------------------------------------------------------
// Kernel 2: fused gather + table MLP + pos add + LayerNorm.
// TWO tokens per wave (8 tokens per 256-thread block): doubles the bytes in
// flight per wave at the same occupancy band, and batches the scalar-load
// heads (expr/gid) of both token chains at wave start. Zero LDS/barriers.
// ---------------------------------------------------------------------------
__global__ __launch_bounds__(256) void fuse_kernel(
        const int*   __restrict__ gene_ids,
        const float* __restrict__ expr,
        const float* __restrict__ gene_emb,
        const float* __restrict__ pos_emb,
        const float* __restrict__ gamma,
        const float* __restrict__ beta,
        const float* __restrict__ tvals,
        const float2* __restrict__ tab,
        float* __restrict__ out) {
    const int tid  = threadIdx.x;
    const int lane = tid & 63;
    const int wv   = tid >> 6;
    const int t0   = blockIdx.x * 8 + wv * 2;       // two consecutive tokens
    const int t1   = t0 + 1;
    const int sp0  = t0 & (S_LEN - 1);              // S = 4096 (pow2)
    const int sp1  = t1 & (S_LEN - 1);

    // --- scalar heads for BOTH tokens + breakpoints: all issue immediately
    const float x0   = expr[t0];
    const float x1   = expr[t1];
    const int   gid0 = gene_ids[t0];
    const int   gid1 = gene_ids[t1];
    const float tka  = tvals[lane];
    const float tkb  = tvals[lane + 64];

    const float4* gp0 = reinterpret_cast<const float4*>(gene_emb + (size_t)gid0 * H_DIM);
    const float4* gp1 = reinterpret_cast<const float4*>(gene_emb + (size_t)gid1 * H_DIM);
    const float4* pp0 = reinterpret_cast<const float4*>(pos_emb  + (size_t)sp0  * H_DIM);
    const float4* pp1 = reinterpret_cast<const float4*>(pos_emb  + (size_t)sp1  * H_DIM);

    // --- gene + pos gathers for both tokens (32 x 16B in flight per lane)
    float4 g0[4], g1[4], p0[4], p1[4];
    #pragma unroll
    for (int q = 0; q < 4; ++q) {
        const int f = lane + 64 * q;
        g0[q] = gp0[f];
        g1[q] = gp1[f];
        p0[q] = pp0[f];
        p1[q] = pp1[f];
    }

    // --- interval rows via ballot+popcount (x is wave-uniform per token)
    const int rc0 = __popcll(__ballot(tka <= x0)) + __popcll(__ballot(tkb <= x0));
    const int rc1 = __popcll(__ballot(tka <= x1)) + __popcll(__ballot(tkb <= x1));

    const bool sp_0 = (x0 < 0.0f);
    const bool sp_1 = (x1 < 0.0f);
    int m0 = min(max(-((int)x0) - 1, 0), NSPEC - 1);
    int m1 = min(max(-((int)x1) - 1, 0), NSPEC - 1);
    const int   row0 = sp_0 ? (HID_DIM + 1 + m0) : rc0;
    const int   row1 = sp_1 ? (HID_DIM + 1 + m1) : rc1;
    const float xm0  = sp_0 ? 0.0f : x0;            // special u-rows are zero
    const float xm1  = sp_1 ? 0.0f : x1;

    // --- table rows for both tokens
    const float4* tp0 = reinterpret_cast<const float4*>(tab + (size_t)row0 * H_DIM);
    const float4* tp1 = reinterpret_cast<const float4*>(tab + (size_t)row1 * H_DIM);
    float4 a0[4], b0[4], a1[4], b1v[4];
    #pragma unroll
    for (int q = 0; q < 4; ++q) {
        const int f = lane + 64 * q;
        a0[q]  = tp0[2 * f];        // (u0, v0, u1, v1)
        b0[q]  = tp0[2 * f + 1];    // (u2, v2, u3, v3)
        a1[q]  = tp1[2 * f];
        b1v[q] = tp1[2 * f + 1];
    }

    // --- gamma/beta (tiny, L1/L2-hot); issue before the reduction chain
    float4 gm[4], bt[4];
    #pragma unroll
    for (int q = 0; q < 4; ++q) {
        const int f = lane + 64 * q;
        gm[q] = reinterpret_cast<const float4*>(gamma)[f];
        bt[q] = reinterpret_cast<const float4*>(beta)[f];
    }

    // --- combine and accumulate moments for both tokens
    float4 e0[4], e1[4];
    float s1_0 = 0.0f, s2_0 = 0.0f, s1_1 = 0.0f, s2_1 = 0.0f;
    #pragma unroll
    for (int q = 0; q < 4; ++q) {
        float4 ev;
        ev.x = g0[q].x + fmaf(xm0, a0[q].x, a0[q].y) + p0[q].x;
        ev.y = g0[q].y + fmaf(xm0, a0[q].z, a0[q].w) + p0[q].y;
        ev.z = g0[q].z + fmaf(xm0, b0[q].x, b0[q].y) + p0[q].z;
        ev.w = g0[q].w + fmaf(xm0, b0[q].z, b0[q].w) + p0[q].w;
        e0[q] = ev;
        s1_0 += ev.x + ev.y + ev.z + ev.w;
        s2_0 += ev.x * ev.x + ev.y * ev.y + ev.z * ev.z + ev.w * ev.w;

        float4 fv;
        fv.x = g1[q].x + fmaf(xm1, a1[q].x, a1[q].y) + p1[q].x;
        fv.y = g1[q].y + fmaf(xm1, a1[q].z, a1[q].w) + p1[q].y;
        fv.z = g1[q].z + fmaf(xm1, b1v[q].x, b1v[q].y) + p1[q].z;
        fv.w = g1[q].w + fmaf(xm1, b1v[q].z, b1v[q].w) + p1[q].w;
        e1[q] = fv;
        s1_1 += fv.x + fv.y + fv.z + fv.w;
        s2_1 += fv.x * fv.x + fv.y * fv.y + fv.z * fv.z + fv.w * fv.w;
    }

    // --- two interleaved 64-lane butterfly reductions (no LDS, no barrier)
    #pragma unroll
    for (int off = 32; off >= 1; off >>= 1) {
        s1_0 += __shfl_xor(s1_0, off, 64);
        s2_0 += __shfl_xor(s2_0, off, 64);
        s1_1 += __shfl_xor(s1_1, off, 64);
        s2_1 += __shfl_xor(s2_1, off, 64);
    }

    const float inv   = 1.0f / (float)H_DIM;
    const float mu0   = s1_0 * inv;
    const float var0  = s2_0 * inv - mu0 * mu0;
    const float rs0   = rsqrtf(var0 + LN_EPS);
    const float mu1   = s1_1 * inv;
    const float var1  = s2_1 * inv - mu1 * mu1;
    const float rs1   = rsqrtf(var1 + LN_EPS);

    vfloat4* op0 = reinterpret_cast<vfloat4*>(out + (size_t)t0 * H_DIM);
    vfloat4* op1 = reinterpret_cast<vfloat4*>(out + (size_t)t1 * H_DIM);
    #pragma unroll
    for (int q = 0; q < 4; ++q) {
        const int f = lane + 64 * q;
        vfloat4 o;
        o.x = fmaf((e0[q].x - mu0) * rs0, gm[q].x, bt[q].x);
        o.y = fmaf((e0[q].y - mu0) * rs0, gm[q].y, bt[q].y);
        o.z = fmaf((e0[q].z - mu0) * rs0, gm[q].z, bt[q].z);
        o.w = fmaf((e0[q].w - mu0) * rs0, gm[q].w, bt[q].w);
        __builtin_nontemporal_store(o, op0 + f);
        vfloat4 o2;
        o2.x = fmaf((e1[q].x - mu1) * rs1, gm[q].x, bt[q].x);
        o2.y = fmaf((e1[q].y - mu1) * rs1, gm[q].y, bt[q].y);
        o2.z = fmaf((e1[q].z - mu1) * rs1, gm[q].z, bt[q].z);
        o2.w = fmaf((e1[q].w - mu1) * rs1, gm[q].w, bt[q].w);
        __builtin_nontemporal_store(o2, op1 + f);
    }
}

// ---------------------------------------------------------------------------
extern "C" void kernel_launch(void* const* d_in, const int* in_sizes, int n_in,
                              void* d_out, int out_size, void* d_ws, size_t ws_size,
                              hipStream_t stream) {
    const int*   gene_ids = (const int*)  d_in[0];
    const float* expr     = (const float*)d_in[1];
    const float* gene_emb = (const float*)d_in[2];
    const float* W1       = (const float*)d_in[3];
    const float* b1       = (const float*)d_in[4];
    const float* W2       = (const float*)d_in[5];
    const float* b2       = (const float*)d_in[6];
    const float* spec     = (const float*)d_in[7];
    const float* pos_emb  = (const float*)d_in[8];
    const float* gamma    = (const float*)d_in[9];
    const float* beta     = (const float*)d_in[10];
    float* out = (float*)d_out;

    // workspace layout
    const size_t tab_bytes = (size_t)NROWS * H_DIM * sizeof(float2);  // ~1.07 MB
    float2* tab   = (float2*)d_ws;
    float*  tvals = (float*)((char*)d_ws + tab_bytes);

    const int n_tokens = in_sizes[0];   // B*S = 32768

    build_kernel<<<NROWS, 256, 0, stream>>>(W1, b1, W2, b2, spec, tvals, tab);
    fuse_kernel<<<n_tokens / 8, 256, 0, stream>>>(gene_ids, expr, gene_emb, pos_emb,
                                                  gamma, beta, tvals, tab, out);
}